// Round 11
// baseline (60.259 us; speedup 1.0000x reference)
//
#include <hip/hip_runtime.h>

#define B 32
#define L 200
#define DIN 64
#define H 64
#define A 36

typedef __attribute__((ext_vector_type(8))) short short8;   // bf16 MFMA fragment
typedef __attribute__((ext_vector_type(4))) float floatx4;  // MFMA accumulator
typedef __attribute__((ext_vector_type(8))) float floatx8;

static __device__ __forceinline__ short f2bf(float f) {
    union { float f; unsigned u; } v; v.f = f;
    unsigned r = (v.u + 0x7FFF + ((v.u >> 16) & 1)) >> 16;  // RNE
    return (short)r;
}
static __device__ __forceinline__ float bf2f(short s) {
    union { unsigned u; float f; } v; v.u = ((unsigned)(unsigned short)s) << 16;
    return v.f;
}

// ONE fused kernel. Block = (b, g): waves own i = 4g+w (consecutive -> balanced).
// Phase 1 (GEMM1): h[j,:] = x[j,:]@ln_w + ln_b for j < MT*16, computed with MFMA
//   (M=hcol, N=j, K=d), written bf16 XOR-swizzled directly to LDS.
// Phase 2: per-wave cc via readlane loop, afrag build from w1 gathers (L1-hot),
//   then the R8 m-loop (6 MFMA + in-lane epilogue + 2 shfl + readlane PV).
__global__ __launch_bounds__(256) void fused_kernel(
    const float* __restrict__ x, const float* __restrict__ ln_w,
    const float* __restrict__ ln_b, const float* __restrict__ w1,
    const float* __restrict__ b1, const float* __restrict__ w2,
    const float* __restrict__ b2, float* __restrict__ out)
{
    int blk = blockIdx.x;
    int b  = blk / 50;
    int g  = 49 - (blk - b * 50);          // longest blocks dispatch first
    int wave = threadIdx.x >> 6;
    int lane = threadIdx.x & 63;
    int i = __builtin_amdgcn_readfirstlane(g * 4 + wave);   // 0..199
    int l15 = lane & 15, l4 = lane >> 4;
    int MT = ((4 * g + 3) >> 4) + 1;       // m-tiles this block materializes (1..13)

    __shared__ __align__(16) short tile[208 * 64];   // bf16 h rows, XOR-swizzled

    const float* xb = x + (size_t)b * L * DIN;

    // ================= Phase 1: GEMM1 h -> LDS =================
    for (int n = 0; n < 4; ++n) {
        floatx4 lnb = *(const floatx4*)(ln_b + n * 16 + l4 * 4);  // C-init bias
        short8 af[2];                       // A: ln_w[k][hcol], hcol = n*16+l15
        #pragma unroll
        for (int s = 0; s < 2; ++s)
            #pragma unroll
            for (int e = 0; e < 8; ++e)
                af[s][e] = f2bf(ln_w[(s * 32 + l4 * 8 + e) * H + n * 16 + l15]);
        for (int mt = wave; mt < MT; mt += 4) {
            int row = mt * 16 + l15;
            int rj = row > L - 1 ? L - 1 : row;      // clamp pad rows
            short8 xf[2];                  // B: x[j][k], j = row
            #pragma unroll
            for (int s = 0; s < 2; ++s) {
                floatx8 xv = *(const floatx8*)(xb + (size_t)rj * DIN + s * 32 + l4 * 8);
                #pragma unroll
                for (int e = 0; e < 8; ++e) xf[s][e] = f2bf(xv[e]);
            }
            floatx4 c = lnb;
            c = __builtin_amdgcn_mfma_f32_16x16x32_bf16(af[0], xf[0], c, 0, 0, 0);
            c = __builtin_amdgcn_mfma_f32_16x16x32_bf16(af[1], xf[1], c, 0, 0, 0);
            // C: hcol = n*16 + l4*4 + r, j = row. Pack 4 bf16, swizzled 8B write.
            unsigned p0 = (unsigned short)f2bf(c[0]) | ((unsigned)(unsigned short)f2bf(c[1]) << 16);
            unsigned p1 = (unsigned short)f2bf(c[2]) | ((unsigned)(unsigned short)f2bf(c[3]) << 16);
            int byte = row * 128 + ((n * 32 + l4 * 8) ^ ((row & 7) << 4));
            uint2 pv; pv.x = p0; pv.y = p1;
            *(uint2*)((char*)tile + byte) = pv;
        }
    }
    __syncthreads();

    // ================= Phase 2: per-wave score =================
    // cc[i,a] + b1[a] via readlane loop (lane = a)
    float hval = bf2f(tile[i * 64 + (lane ^ ((i & 7) << 3))]);   // h_i[lane]
    float cb = (lane < A) ? b1[lane] : 0.f;
    const float* w1b = w1 + (size_t)H * A;
    #pragma unroll 8
    for (int k = 0; k < H; ++k) {
        float hk = __int_as_float(
            __builtin_amdgcn_readlane(__float_as_int(hval), k));  // SGPR h_i[k]
        cb = fmaf(hk, w1b[k * A + lane], cb);   // coalesced 144B load, L1-hot
    }
    float b2v = b2[0];
    float cbv[3][4], w2v[3][4];
    #pragma unroll
    for (int n = 0; n < 3; ++n)
        #pragma unroll
        for (int r = 0; r < 4; ++r) {
            int a = n * 16 + l4 * 4 + r;
            float v = __shfl(cb, a, 64);
            cbv[n][r] = (a < A) ? v : 0.f;
            w2v[n][r] = (a < A) ? w2[a] : 0.f;
        }
    // afrag: B_i[k,c] = w1a[k,c] + h_i[k]*w1c[k,c]; k = s*32+l4*8+e, c = n*16+l15
    short8 afrag[2][3];
    #pragma unroll
    for (int s = 0; s < 2; ++s) {
        short8 hraw = *(const short8*)(tile + i * 64 + ((s * 32 + l4 * 8) ^ ((i & 7) << 3)));
        float hik[8];
        #pragma unroll
        for (int e = 0; e < 8; ++e) hik[e] = bf2f(hraw[e]);
        #pragma unroll
        for (int n = 0; n < 3; ++n) {
            int c = n * 16 + l15;
            bool cv = c < A;
            #pragma unroll
            for (int e = 0; e < 8; ++e) {
                int k = s * 32 + l4 * 8 + e;
                float wa = cv ? w1[k * A + c] : 0.f;                  // w1a, L1-hot
                float wc = cv ? w1[(2 * H + k) * A + c] : 0.f;        // w1c, L1-hot
                afrag[s][n][e] = f2bf(fmaf(hik[e], wc, wa));
            }
        }
    }

    float oacc[4] = {0.f, 0.f, 0.f, 0.f};
    int mmax = (i >> 4) + 1;   // wave-uniform

    for (int m = 0; m < mmax; ++m) {
        int row = m * 16 + l15;
        const short* brow = tile + row * 64;
        int sw = (l15 & 7) << 3;
        short8 bf0 = *(const short8*)(brow + ((l4 * 8) ^ sw));
        short8 bf1 = *(const short8*)(brow + ((32 + l4 * 8) ^ sw));
        floatx4 c0 = {cbv[0][0], cbv[0][1], cbv[0][2], cbv[0][3]};
        floatx4 c1 = {cbv[1][0], cbv[1][1], cbv[1][2], cbv[1][3]};
        floatx4 c2 = {cbv[2][0], cbv[2][1], cbv[2][2], cbv[2][3]};
        c0 = __builtin_amdgcn_mfma_f32_16x16x32_bf16(afrag[0][0], bf0, c0, 0, 0, 0);
        c1 = __builtin_amdgcn_mfma_f32_16x16x32_bf16(afrag[0][1], bf0, c1, 0, 0, 0);
        c2 = __builtin_amdgcn_mfma_f32_16x16x32_bf16(afrag[0][2], bf0, c2, 0, 0, 0);
        c0 = __builtin_amdgcn_mfma_f32_16x16x32_bf16(afrag[1][0], bf1, c0, 0, 0, 0);
        c1 = __builtin_amdgcn_mfma_f32_16x16x32_bf16(afrag[1][1], bf1, c1, 0, 0, 0);
        c2 = __builtin_amdgcn_mfma_f32_16x16x32_bf16(afrag[1][2], bf1, c2, 0, 0, 0);
        float sp0 = 0.f, sp1 = 0.f, sp2 = 0.f;
        #pragma unroll
        for (int r = 0; r < 4; ++r) {
            sp0 = fmaf(fmaxf(c0[r], 0.01f * c0[r]), w2v[0][r], sp0);
            sp1 = fmaf(fmaxf(c1[r], 0.01f * c1[r]), w2v[1][r], sp1);
            sp2 = fmaf(fmaxf(c2[r], 0.01f * c2[r]), w2v[2][r], sp2);
        }
        float sp = (sp0 + sp1) + sp2;
        sp += __shfl_xor(sp, 16, 64);
        sp += __shfl_xor(sp, 32, 64);          // score[j=m*16+l15] in all lanes
        float sc = (row <= i) ? sp + b2v : 0.f;

        // PV: h from LDS (bf16), score broadcast via readlane
        #pragma unroll
        for (int rb = 0; rb < 4; ++rb) {
            #pragma unroll
            for (int q = 0; q < 4; ++q) {
                int jq = rb * 4 + q;
                int jr = m * 16 + jq;
                float sq = __int_as_float(
                    __builtin_amdgcn_readlane(__float_as_int(sc), jq));
                float hv = bf2f(tile[jr * 64 + (lane ^ ((jr & 7) << 3))]);
                oacc[rb] = fmaf(sq, hv, oacc[rb]);
            }
        }
    }

    out[((size_t)b * L + i) * H + lane] = (oacc[0] + oacc[1]) + (oacc[2] + oacc[3]);
}

extern "C" void kernel_launch(void* const* d_in, const int* in_sizes, int n_in,
                              void* d_out, int out_size, void* d_ws, size_t ws_size,
                              hipStream_t stream) {
    const float* x    = (const float*)d_in[0];
    const float* ln_w = (const float*)d_in[1];
    const float* ln_b = (const float*)d_in[2];
    const float* w1   = (const float*)d_in[3];
    const float* b1   = (const float*)d_in[4];
    const float* w2   = (const float*)d_in[5];
    const float* b2   = (const float*)d_in[6];
    float* out = (float*)d_out;

    fused_kernel<<<B * 50, 256, 0, stream>>>(x, ln_w, ln_b, w1, b1, w2, b2, out);
}

// Round 12
// 43.394 us; speedup vs baseline: 1.3886x; 1.3886x over previous
//
#include <hip/hip_runtime.h>

#define B 32
#define L 200
#define DIN 64
#define H 64
#define A 36

typedef __attribute__((ext_vector_type(8))) short short8;   // bf16 MFMA fragment
typedef __attribute__((ext_vector_type(4))) float floatx4;  // MFMA accumulator
typedef __attribute__((ext_vector_type(8))) float floatx8;

static __device__ __forceinline__ short f2bf(float f) {
    union { float f; unsigned u; } v; v.f = f;
    unsigned r = (v.u + 0x7FFF + ((v.u >> 16) & 1)) >> 16;  // RNE
    return (short)r;
}

// Kernel 1: h = x@ln_w + ln_b ; h f32, hb16 LINEAR bf16, cc = h@w1b.
// Block 0 also reorders w1a/w1c into MFMA-fragment order (f32).
__global__ __launch_bounds__(256) void prep_kernel(
    const float* __restrict__ x, const float* __restrict__ ln_w,
    const float* __restrict__ ln_b, const float* __restrict__ w1,
    float* __restrict__ h_out, float* __restrict__ cc_out, short* __restrict__ hb16_out,
    float* __restrict__ w1a_r, float* __restrict__ w1c_r)
{
    int wave = threadIdx.x >> 6;
    int lane = threadIdx.x & 63;
    int bl = __builtin_amdgcn_readfirstlane(blockIdx.x * 4 + wave);
    const float* xr = x + (size_t)bl * DIN;
    float p0 = ln_b[lane], p1 = 0.f;
    #pragma unroll
    for (int d = 0; d < DIN; d += 2) {
        p0 = fmaf(xr[d],     ln_w[d * H + lane],       p0);   // xr uniform -> s_load
        p1 = fmaf(xr[d + 1], ln_w[(d + 1) * H + lane], p1);
    }
    float acc = p0 + p1;
    __shared__ float hrow[4][H];
    hrow[wave][lane] = acc;
    h_out[(size_t)bl * H + lane] = acc;
    hb16_out[(size_t)bl * H + lane] = f2bf(acc);              // linear layout
    if (lane < A) {
        float s0 = 0.f, s1 = 0.f;
        #pragma unroll
        for (int hh = 0; hh < H; hh += 2) {
            s0 = fmaf(hrow[wave][hh],     w1[(H + hh) * A + lane],     s0);   // w1b
            s1 = fmaf(hrow[wave][hh + 1], w1[(H + hh + 1) * A + lane], s1);
        }
        cc_out[(size_t)bl * A + lane] = s0 + s1;
    }
    if (blockIdx.x == 0) {
        // fragment-order tables: idx = ((s*3+n)*64 + lane)*8 + e
        for (int idx = threadIdx.x; idx < 2 * 3 * 64 * 8; idx += 256) {
            int e = idx & 7, ln = (idx >> 3) & 63, sn = idx >> 9;
            int s = sn / 3, n = sn - 3 * s;
            int k = s * 32 + (ln >> 4) * 8 + e;
            int c = n * 16 + (ln & 15);
            w1a_r[idx] = (c < A) ? w1[k * A + c] : 0.f;
            w1c_r[idx] = (c < A) ? w1[(2 * H + k) * A + c] : 0.f;
        }
    }
}

// Kernel 2: block=(b,bg), bg 0..49; wave w owns i = bg + 50w.
// NO LDS, NO barriers, NO staging: hb16 (25.6 KB/b, L1/L2-fit) is read directly
// from global as MFMA B-fragments (2x dwordx4 per m-iter); PV reads f32 h from
// global; score broadcast via readlane. Waves fully independent.
__global__ __launch_bounds__(256) void score_kernel(
    const float* __restrict__ h, const short* __restrict__ hb16,
    const float* __restrict__ cc, const float* __restrict__ w1a_r,
    const float* __restrict__ w1c_r, const float* __restrict__ b1,
    const float* __restrict__ w2, const float* __restrict__ b2,
    float* __restrict__ out)
{
    int blk = blockIdx.x;
    int b  = blk / 50;
    int bg = blk - b * 50;
    int wave = threadIdx.x >> 6;
    int lane = threadIdx.x & 63;
    int i = __builtin_amdgcn_readfirstlane(bg + 50 * wave);
    int l15 = lane & 15, l4 = lane >> 4;

    const short* hb16b = hb16 + (size_t)b * L * H;
    const float* h_b   = h + (size_t)b * L * H;

    // ---- prologue ----
    const float* hi    = h_b + (size_t)i * H;             // uniform -> s_load
    const float* ccrow = cc + ((size_t)b * L + i) * A;
    float b2v = b2[0];
    float w2v[3][4], cbv[3][4];
    #pragma unroll
    for (int n = 0; n < 3; ++n) {
        #pragma unroll
        for (int r = 0; r < 4; ++r) {
            int a = n * 16 + l4 * 4 + r;       // this lane's C row for tile n, reg r
            bool av = a < A;
            w2v[n][r] = av ? w2[a] : 0.f;
            cbv[n][r] = av ? (ccrow[a] + b1[a]) : 0.f;
        }
    }
    short8 afrag[2][3];                        // A-operand: B_i[a = n*16+l15][k]
    #pragma unroll
    for (int s = 0; s < 2; ++s) {
        float hik[8];
        #pragma unroll
        for (int e = 0; e < 8; ++e) hik[e] = hi[s * 32 + l4 * 8 + e];
        #pragma unroll
        for (int n = 0; n < 3; ++n) {
            floatx8 wa = *(const floatx8*)&w1a_r[(((s * 3 + n) * 64) + lane) * 8];
            floatx8 wc = *(const floatx8*)&w1c_r[(((s * 3 + n) * 64) + lane) * 8];
            #pragma unroll
            for (int e = 0; e < 8; ++e)
                afrag[s][n][e] = f2bf(fmaf(hik[e], wc[e], wa[e]));
        }
    }

    float oacc[4] = {0.f, 0.f, 0.f, 0.f};
    int mmax = (i >> 4) + 1;   // wave-uniform

    for (int m = 0; m < mmax; ++m) {
        // B-fragment: h[j = m*16+l15][k] straight from global (L1/L2-hot)
        int row = m * 16 + l15;
        int rj = row > L - 1 ? L - 1 : row;            // clamp (masked below)
        const short* brow = hb16b + (size_t)rj * H;
        short8 bf0 = *(const short8*)(brow + l4 * 8);         // global_load_dwordx4
        short8 bf1 = *(const short8*)(brow + 32 + l4 * 8);
        floatx4 c0 = {cbv[0][0], cbv[0][1], cbv[0][2], cbv[0][3]};
        floatx4 c1 = {cbv[1][0], cbv[1][1], cbv[1][2], cbv[1][3]};
        floatx4 c2 = {cbv[2][0], cbv[2][1], cbv[2][2], cbv[2][3]};
        c0 = __builtin_amdgcn_mfma_f32_16x16x32_bf16(afrag[0][0], bf0, c0, 0, 0, 0);
        c1 = __builtin_amdgcn_mfma_f32_16x16x32_bf16(afrag[0][1], bf0, c1, 0, 0, 0);
        c2 = __builtin_amdgcn_mfma_f32_16x16x32_bf16(afrag[0][2], bf0, c2, 0, 0, 0);
        c0 = __builtin_amdgcn_mfma_f32_16x16x32_bf16(afrag[1][0], bf1, c0, 0, 0, 0);
        c1 = __builtin_amdgcn_mfma_f32_16x16x32_bf16(afrag[1][1], bf1, c1, 0, 0, 0);
        c2 = __builtin_amdgcn_mfma_f32_16x16x32_bf16(afrag[1][2], bf1, c2, 0, 0, 0);
        // epilogue: leaky = max(x, 0.01x); 3 independent w2-dot chains; 2 shfl rounds
        float sp0 = 0.f, sp1 = 0.f, sp2 = 0.f;
        #pragma unroll
        for (int r = 0; r < 4; ++r) {
            sp0 = fmaf(fmaxf(c0[r], 0.01f * c0[r]), w2v[0][r], sp0);
            sp1 = fmaf(fmaxf(c1[r], 0.01f * c1[r]), w2v[1][r], sp1);
            sp2 = fmaf(fmaxf(c2[r], 0.01f * c2[r]), w2v[2][r], sp2);
        }
        float sp = (sp0 + sp1) + sp2;
        sp += __shfl_xor(sp, 16, 64);
        sp += __shfl_xor(sp, 32, 64);          // all lanes: full a-sum for j = m*16+l15
        float sc = (row <= i) ? sp + b2v : 0.f;

        // PV: coalesced f32 global reads of h rows; score via readlane (SGPR)
        const float* hjb = h_b + (size_t)(m * 16) * H + lane;
        #pragma unroll
        for (int rb = 0; rb < 4; ++rb) {
            #pragma unroll
            for (int q = 0; q < 4; ++q) {
                int jq = rb * 4 + q;
                float sq = __int_as_float(
                    __builtin_amdgcn_readlane(__float_as_int(sc), jq));
                float hv = hjb[jq * H];        // dword, imm offset, L1/L2-hot
                oacc[rb] = fmaf(sq, hv, oacc[rb]);
            }
        }
    }

    out[((size_t)b * L + i) * H + lane] = (oacc[0] + oacc[1]) + (oacc[2] + oacc[3]);
}

extern "C" void kernel_launch(void* const* d_in, const int* in_sizes, int n_in,
                              void* d_out, int out_size, void* d_ws, size_t ws_size,
                              hipStream_t stream) {
    const float* x    = (const float*)d_in[0];
    const float* ln_w = (const float*)d_in[1];
    const float* ln_b = (const float*)d_in[2];
    const float* w1   = (const float*)d_in[3];
    const float* b1   = (const float*)d_in[4];
    const float* w2   = (const float*)d_in[5];
    const float* b2   = (const float*)d_in[6];
    float* out = (float*)d_out;

    float* h_ws   = (float*)d_ws;                             // B*L*H f32
    float* cc_ws  = h_ws + (size_t)B * L * H;                 // B*L*A f32
    short* hb16_ws = (short*)(cc_ws + (size_t)B * L * A);     // B*L*H bf16 (linear)
    float* w1a_r  = (float*)(hb16_ws + (size_t)B * L * H);    // 3072 f32
    float* w1c_r  = w1a_r + 3072;                             // 3072 f32

    prep_kernel<<<(B * L) / 4, 256, 0, stream>>>(x, ln_w, ln_b, w1, h_ws, cc_ws,
                                                 hb16_ws, w1a_r, w1c_r);
    score_kernel<<<B * 50, 256, 0, stream>>>(h_ws, hb16_ws, cc_ws, w1a_r, w1c_r,
                                             b1, w2, b2, out);
}